// Round 6
// baseline (271.050 us; speedup 1.0000x reference)
//
#include <hip/hip_runtime.h>
#include <math.h>

// BatchHardTripletMarginLoss on MI355X — round 6: DMA-staged mine, 3 dispatches.
// Pipeline (all on `stream`, graph-capture safe):
//   prep    : [blocks 0..1023] E fp32->fp16 + sq; zero finalize ticket
//             [blocks 1024..5119] per-block mask-format sniff (shared 16 KB
//             window) + positives_mask -> packed bitmask via __ballot
//   mine    : fp16 MFMA Gram 128x128/block, BK=64, staging via
//             global_load_lds (16B DMA, no VGPR round-trip — round-5's
//             register prefetch spilled 83 MB to scratch), XOR-swizzled LDS
//             (involution: lane fetches granule (lane&7)^swz(row) so the
//             DMA's lane-contiguous LDS layout == swizzled layout)
//   finalize: fused combine (32-chunk argmax/argmin) + fp32 distance
//             recompute + last-block ticket reduce -> out
// Accuracy: fp16 only affects WHICH indices are mined (d2 err ~0.02 vs rival
// gaps ~13); the loss values are recomputed in fp32.

#define NN 4096
#define DD 256
#define MARGIN 0.2f
#define NCHUNK 32            // one 128-col j-tile per chunk
#define BK 64                // K-chunk in halves (2 MFMA substeps)

typedef _Float16 f16;
typedef __attribute__((ext_vector_type(8))) _Float16 f16x8;
typedef __attribute__((ext_vector_type(4))) _Float16 f16x4;
typedef __attribute__((ext_vector_type(4))) float f32x4;
typedef unsigned long long u64;

// ws byte offsets
#define OFF_TICKET 0                                     // finalize completion counter
#define OFF_SQ     64                                    // 16 KB
#define OFF_EH     (OFF_SQ + NN * 4)                     // 2 MB fp16 embeddings
#define OFF_POSB   (OFF_EH + NN * DD * 2)                // 2 MB packed positives
#define OFF_PPV    (OFF_POSB + (NN * (long)NN / 8))      // 512 KB each partial
#define OFF_PPI    (OFF_PPV + NN * NCHUNK * 4)
#define OFF_PNV    (OFF_PPI + NN * NCHUNK * 4)
#define OFF_PNI    (OFF_PNV + NN * NCHUNK * 4)
#define OFF_LOSS   (OFF_PNI + NN * NCHUNK * 4)           // 16 KB per-anchor losses

#define CONV_BLOCKS   (NN / 4)                           // 1024
#define REPACK_BLOCKS 4096                               // 16 elements/thread
#define PREP_BLOCKS   (CONV_BLOCKS + REPACK_BLOCKS)

// ---------------------------------------------------------------------------
// XOR swizzle: row stride 64 halves (128 B = all 32 banks); 16-B granule g of
// row r stored at slot g ^ swz(r). Involution: slot s holds granule s^swz(r).
__device__ __forceinline__ int swz(int r) { return (r ^ (r >> 3)) & 7; }

// 16-B global->LDS DMA (lane dest = lds base + lane*16, wave-uniform base).
__device__ __forceinline__ void dma16(const void* g, void* l) {
  __builtin_amdgcn_global_load_lds(
      (const __attribute__((address_space(1))) void*)g,
      (__attribute__((address_space(3))) void*)l, 16, 0, 0);
}

// ---------------------------------------------------------------------------
// prep: convert (blocks 0..CONV_BLOCKS-1) | repack+sniff (the rest).
// Sniff window: first 16 KB of positives_mask — dense enough in every
// candidate encoding (int32 ~64 ones, u8 ~256, f32 ~64, i64/f64 ~32).
__global__ __launch_bounds__(256)
void prep_kernel(const float* __restrict__ E, const void* __restrict__ pos_raw,
                 f16* __restrict__ Eh, float* __restrict__ sq,
                 u64* __restrict__ posb, int* __restrict__ ticket) {
  const int bid = blockIdx.x;
  const int tid = threadIdx.x;
  if (bid < CONV_BLOCKS) {
    if (bid == 0 && tid == 0) *ticket = 0;
    const int row = bid * 4 + (tid >> 6);
    const int lane = tid & 63;
    const float4 v = *(const float4*)&E[(size_t)row * DD + lane * 4];
    f16x4 h;
    h[0] = (f16)v.x; h[1] = (f16)v.y; h[2] = (f16)v.z; h[3] = (f16)v.w;
    *(f16x4*)&Eh[(size_t)row * DD + lane * 4] = h;
    float s = v.x * v.x + v.y * v.y + v.z * v.z + v.w * v.w;
#pragma unroll
    for (int off = 32; off > 0; off >>= 1) s += __shfl_down(s, off);
    if (lane == 0) sq[row] = s;
    return;
  }

  // ---- repack branch ----
  __shared__ int s_ev[4];
  // format sniff: evidence bits 1=u8, 2=f32, 4=f64(odd 1.0-hi), 8=odd-dword
  int ev = 0;
#pragma unroll
  for (int k = 0; k < 16; ++k) {
    const int di = tid + (k << 8);                       // 4096 dwords = 16 KB
    const unsigned int v = ((const unsigned int*)pos_raw)[di];
    if (v & 0xffffff00u) ev |= 1;
    if (v == 0x3f800000u) ev |= 2;
    if (di & 1) {
      if (v == 0x3ff00000u) ev |= 4;
      if (v) ev |= 8;
    }
  }
#pragma unroll
  for (int off = 32; off > 0; off >>= 1) ev |= __shfl_xor(ev, off);
  if ((tid & 63) == 0) s_ev[tid >> 6] = ev;
  __syncthreads();
  ev = s_ev[0] | s_ev[1] | s_ev[2] | s_ev[3];
  int f;                                                  // 0=i32 1=u8 2=f32 3=i64 4=f64
  if (ev & 2) f = 2;
  else if (ev & 4) f = 4;
  else if (ev & 1) f = 1;
  else if (ev & 8) f = 0;
  else f = 3;

  const long long stride = (long long)REPACK_BLOCKS * 256;  // 1,048,576
  const long long base = (long long)(bid - CONV_BLOCKS) * 256 + tid;
#pragma unroll
  for (int it = 0; it < 16; ++it) {
    const long long idx = base + it * stride;
    bool p;
    if (f == 0)      p = ((const unsigned int*)pos_raw)[idx] != 0u;
    else if (f == 1) p = ((const unsigned char*)pos_raw)[idx] != 0;
    else if (f == 2) p = ((const float*)pos_raw)[idx] != 0.f;
    else if (f == 3) p = ((const u64*)pos_raw)[idx] != 0ull;
    else             p = ((const double*)pos_raw)[idx] != 0.0;
    const u64 w = __ballot(p);
    if ((tid & 63) == 0) posb[idx >> 6] = w;
  }
}

// ---------------------------------------------------------------------------
// MFMA Gram + batch-hard mining. 128x128 tile/block; 4 waves in a 2x2 grid,
// each wave a 4x4 grid of 16x16x32_f16 MFMAs. Staging: global_load_lds DMA,
// 8 issues/wave/chunk (A:4, B:4), each issue = 8 rows x 128 B. No staging
// VGPRs -> no spill (round-5 lesson). Epilogue: per-row masked max/min with
// index, quad-butterfly + LDS cross-wave reduce -> per-chunk partials.
__global__ __launch_bounds__(256)
void mine_kernel(const f16* __restrict__ Eh, const float* __restrict__ sq,
                 const u64* __restrict__ posb,
                 float* __restrict__ part_pv, int* __restrict__ part_pi,
                 float* __restrict__ part_nv, int* __restrict__ part_ni) {
  __shared__ union {
    struct { f16 A[128 * BK]; f16 B[128 * BK]; } t;                   // 32 KB
    struct { float pv[2][128]; int pi[2][128];
             float nv[2][128]; int ni[2][128]; } r;                   // 4 KB
  } sm;

  const int tid = threadIdx.x;
  const int lane = tid & 63, wave = tid >> 6;
  const int lx = lane & 15, q = lane >> 4;
  const int wr = wave >> 1, wc = wave & 1;
  const int ib = blockIdx.x & 31, jb = blockIdx.x >> 5;
  const int i0 = ib * 128, j0 = jb * 128;

  f32x4 acc[4][4];
#pragma unroll
  for (int mt = 0; mt < 4; ++mt)
#pragma unroll
    for (int nt = 0; nt < 4; ++nt) acc[mt][nt] = (f32x4)0.f;

  // DMA source pattern: issue i covers rows 8i..8i+7; lane ld = row 8i+(ld>>3),
  // slot ld&7, fetches granule (ld&7)^swz(row) -> swizzled layout lands right.
  const int drow = lane >> 3;            // 0..7 within issue
  const int dslot = lane & 7;

  for (int kk = 0; kk < DD; kk += BK) {
    __syncthreads();                      // prev chunk's frag reads done
#pragma unroll
    for (int t = 0; t < 4; ++t) {
      const int i = wave * 4 + t;         // issue 0..15
      const int r = i * 8 + drow;         // tile row 0..127
      const int g = dslot ^ swz(r);
      dma16(Eh + (size_t)(i0 + r) * DD + kk + g * 8, &sm.t.A[i * 512]);
      dma16(Eh + (size_t)(j0 + r) * DD + kk + g * 8, &sm.t.B[i * 512]);
    }
    __syncthreads();                      // compiler drains vmcnt before barrier
#pragma unroll
    for (int ss = 0; ss < 2; ++ss) {
      f16x8 af[4], bf[4];
#pragma unroll
      for (int mt = 0; mt < 4; ++mt) {
        const int r = wr * 64 + mt * 16 + lx;
        af[mt] = *(const f16x8*)&sm.t.A[r * BK + (((ss * 4 + q) ^ swz(r)) << 3)];
      }
#pragma unroll
      for (int nt = 0; nt < 4; ++nt) {
        const int r = wc * 64 + nt * 16 + lx;
        bf[nt] = *(const f16x8*)&sm.t.B[r * BK + (((ss * 4 + q) ^ swz(r)) << 3)];
      }
#pragma unroll
      for (int mt = 0; mt < 4; ++mt)
#pragma unroll
        for (int nt = 0; nt < 4; ++nt)
          acc[mt][nt] = __builtin_amdgcn_mfma_f32_16x16x32_f16(af[mt], bf[nt], acc[mt][nt], 0, 0, 0);
    }
  }

  // ------- epilogue: d2 + masked mining -------
  float sqj[4];
#pragma unroll
  for (int nt = 0; nt < 4; ++nt) sqj[nt] = sq[j0 + wc * 64 + nt * 16 + lx];
  const int jw = (j0 + wc * 64) >> 6;  // mask word index for this wave's 64 cols

  __syncthreads();  // all frag reads done; LDS becomes the mining buffer

#pragma unroll
  for (int mt = 0; mt < 4; ++mt) {
#pragma unroll
    for (int r = 0; r < 4; ++r) {
      const int lr = wr * 64 + mt * 16 + q * 4 + r;   // local row 0..127
      const int gi = i0 + lr;
      const float sqi = sq[gi];
      const u64 pw = posb[(size_t)gi * (NN / 64) + jw];
      const u64 nw = ~(pw | (((gi >> 6) == jw) ? (1ull << (gi & 63)) : 0ull));
      float pb = -1e30f, nb = 1e30f;
      int pi_ = 1 << 30, ni_ = 1 << 30;
#pragma unroll
      for (int nt = 0; nt < 4; ++nt) {
        const int c = nt * 16 + lx;                    // col within the 64-word
        const int gj = j0 + wc * 64 + c;
        const float d2 = fmaxf(fmaf(-2.f, acc[mt][nt][r], sqi + sqj[nt]), 0.f);
        if ((pw >> c) & 1ull) { if (d2 > pb) { pb = d2; pi_ = gj; } }
        if ((nw >> c) & 1ull) { if (d2 < nb) { nb = d2; ni_ = gj; } }
      }
      // butterfly across the 16 lanes of this quad (offsets < 16 stay in-quad)
#pragma unroll
      for (int off = 1; off < 16; off <<= 1) {
        float ov = __shfl_xor(pb, off); int oi = __shfl_xor(pi_, off);
        if (ov > pb || (ov == pb && oi < pi_)) { pb = ov; pi_ = oi; }
        ov = __shfl_xor(nb, off); oi = __shfl_xor(ni_, off);
        if (ov < nb || (ov == nb && oi < ni_)) { nb = ov; ni_ = oi; }
      }
      if (lx == 0) {
        sm.r.pv[wc][lr] = pb; sm.r.pi[wc][lr] = pi_;
        sm.r.nv[wc][lr] = nb; sm.r.ni[wc][lr] = ni_;
      }
    }
  }

  __syncthreads();
  if (tid < 128) {
    float pv = sm.r.pv[0][tid]; int pi_ = sm.r.pi[0][tid];
    float nv = sm.r.nv[0][tid]; int ni_ = sm.r.ni[0][tid];
    const float pv1 = sm.r.pv[1][tid]; const int pi1 = sm.r.pi[1][tid];
    const float nv1 = sm.r.nv[1][tid]; const int ni1 = sm.r.ni[1][tid];
    if (pv1 > pv) { pv = pv1; pi_ = pi1; }   // wc=0 has lower cols: ties keep wc0
    if (nv1 < nv) { nv = nv1; ni_ = ni1; }
    const size_t o = (size_t)(i0 + tid) * NCHUNK + jb;
    part_pv[o] = pv; part_pi[o] = pi_;
    part_nv[o] = nv; part_ni[o] = ni_;
  }
}

// ---------------------------------------------------------------------------
// Fused combine + finalize + last-block reduce. One wave per anchor: lanes
// 0..31 reduce the 32 positive-chunk partials (argmax), lanes 32..63 the
// negative ones (argmin via negated key); ties keep the smallest index
// (reference first-index semantics; chunk order == index order). Then fp32
// recompute of the three distances -> loss[a]. Last block (device-scope
// ticket) reduces loss[] and writes the scalar output.
__global__ __launch_bounds__(256)
void finalize_kernel(const float* __restrict__ E, const float* __restrict__ sq,
                     const float* __restrict__ ppv, const int* __restrict__ ppi,
                     const float* __restrict__ pnv, const int* __restrict__ pni,
                     float* __restrict__ loss, int* __restrict__ ticket,
                     float* __restrict__ out) {
  __shared__ int s_ticket;
  __shared__ float s_sum[4], s_cnt[4];
  const int tid = threadIdx.x;
  const int a = blockIdx.x * 4 + (tid >> 6);
  const int lane = tid & 63;
  const int ch = lane & 31;
  float key; int idx;
  if (lane < 32) { key = ppv[(size_t)a * NCHUNK + ch]; idx = ppi[(size_t)a * NCHUNK + ch]; }
  else           { key = -pnv[(size_t)a * NCHUNK + ch]; idx = pni[(size_t)a * NCHUNK + ch]; }
#pragma unroll
  for (int off = 1; off < 32; off <<= 1) {   // stays within each 32-lane half
    const float ok = __shfl_xor(key, off); const int oi = __shfl_xor(idx, off);
    if (ok > key || (ok == key && oi < idx)) { key = ok; idx = oi; }
  }
  const int p = __shfl(idx, 0);
  const int n = __shfl(idx, 32);
  const bool valid = (p < NN) && (n < NN);
  const int pp = valid ? p : 0, nn = valid ? n : 0;

  const float4 xa = *(const float4*)&E[(size_t)a * DD + lane * 4];
  const float4 xp = *(const float4*)&E[(size_t)pp * DD + lane * 4];
  const float4 xn = *(const float4*)&E[(size_t)nn * DD + lane * 4];
  float dap = xa.x * xp.x + xa.y * xp.y + xa.z * xp.z + xa.w * xp.w;
  float dan = xa.x * xn.x + xa.y * xn.y + xa.z * xn.z + xa.w * xn.w;
  float dpn = xp.x * xn.x + xp.y * xn.y + xp.z * xn.z + xp.w * xn.w;
#pragma unroll
  for (int off = 32; off > 0; off >>= 1) {
    dap += __shfl_down(dap, off);
    dan += __shfl_down(dan, off);
    dpn += __shfl_down(dpn, off);
  }
  if (lane == 0) {
    float l = 0.f;
    if (valid) {
      const float d2ap = fmaxf(sq[a] + sq[pp] - 2.f * dap, 0.f);
      const float d2an = fmaxf(sq[a] + sq[nn] - 2.f * dan, 0.f);
      const float d2pn = fmaxf(sq[pp] + sq[nn] - 2.f * dpn, 0.f);
      l = fmaxf(sqrtf(d2ap) - fminf(sqrtf(d2an), sqrtf(d2pn)) + MARGIN, 0.f);
    }
    loss[a] = l;
  }

  // ---- last-block reduction (threadFenceReduction pattern) ----
  __threadfence();
  __syncthreads();
  if (tid == 0) s_ticket = atomicAdd(ticket, 1);
  __syncthreads();
  if (s_ticket == (int)gridDim.x - 1) {
    __threadfence();                       // acquire: see all blocks' loss stores
    const float4 v = *(const float4*)&loss[tid * 4];       // 1024 float4 / 256 thr
    const float4 v2 = *(const float4*)&loss[NN / 2 + tid * 4];
    const float4 v3 = *(const float4*)&loss[NN / 4 + tid * 4];
    const float4 v4 = *(const float4*)&loss[3 * NN / 4 + tid * 4];
    float s = v.x + v.y + v.z + v.w + v2.x + v2.y + v2.z + v2.w +
              v3.x + v3.y + v3.z + v3.w + v4.x + v4.y + v4.z + v4.w;
    float c = (v.x > 0.f) + (v.y > 0.f) + (v.z > 0.f) + (v.w > 0.f) +
              (v2.x > 0.f) + (v2.y > 0.f) + (v2.z > 0.f) + (v2.w > 0.f) +
              (v3.x > 0.f) + (v3.y > 0.f) + (v3.z > 0.f) + (v3.w > 0.f) +
              (v4.x > 0.f) + (v4.y > 0.f) + (v4.z > 0.f) + (v4.w > 0.f);
#pragma unroll
    for (int off = 32; off > 0; off >>= 1) {
      s += __shfl_down(s, off);
      c += __shfl_down(c, off);
    }
    if ((tid & 63) == 0) { s_sum[tid >> 6] = s; s_cnt[tid >> 6] = c; }
    __syncthreads();
    if (tid == 0) {
      const float ts = s_sum[0] + s_sum[1] + s_sum[2] + s_sum[3];
      const float tc = s_cnt[0] + s_cnt[1] + s_cnt[2] + s_cnt[3];
      out[0] = (tc > 0.f) ? (ts / fmaxf(tc, 1.f)) : 0.f;
    }
  }
}

// ---------------------------------------------------------------------------
extern "C" void kernel_launch(void* const* d_in, const int* in_sizes, int n_in,
                              void* d_out, int out_size, void* d_ws, size_t ws_size,
                              hipStream_t stream) {
  const float* E = (const float*)d_in[0];
  const void* posm = d_in[1];
  float* out = (float*)d_out;
  char* ws = (char*)d_ws;

  int* ticket = (int*)(ws + OFF_TICKET);
  float* sq = (float*)(ws + OFF_SQ);
  f16* Eh = (f16*)(ws + OFF_EH);
  u64* posb = (u64*)(ws + OFF_POSB);
  float* ppv = (float*)(ws + OFF_PPV);
  int* ppi = (int*)(ws + OFF_PPI);
  float* pnv = (float*)(ws + OFF_PNV);
  int* pni = (int*)(ws + OFF_PNI);
  float* loss = (float*)(ws + OFF_LOSS);

  prep_kernel<<<PREP_BLOCKS, 256, 0, stream>>>(E, posm, Eh, sq, posb, ticket);
  mine_kernel<<<32 * NCHUNK, 256, 0, stream>>>(Eh, sq, posb, ppv, ppi, pnv, pni);
  finalize_kernel<<<NN / 4, 256, 0, stream>>>(E, sq, ppv, ppi, pnv, pni, loss, ticket, out);
}

// Round 7
// 210.767 us; speedup vs baseline: 1.2860x; 1.2860x over previous
//
#include <hip/hip_runtime.h>
#include <math.h>

// BatchHardTripletMarginLoss on MI355X — round 7: no device-scope fences.
// Pipeline (all on `stream`, graph-capture safe):
//   prep    : [blocks 0..1023] E fp32->fp16 + sq
//             [blocks 1024..5119] per-block mask-format sniff (shared 16 KB
//             window) + positives_mask -> packed bitmask via __ballot
//   mine    : fp16 MFMA Gram 128x128/block, BK=64, staging via
//             global_load_lds (16B DMA, no VGPR round-trip), XOR-swizzled LDS
//   finalize: fused combine (32-chunk argmax/argmin) + fp32 distance
//             recompute -> loss[a]   (NO ticket/threadfence: round-6's 70 us
//             was agent-scope fence = per-XCD L2 writeback+invalidate x1024)
//   reduce  : single-block tree-reduce of loss[] -> out
// Accuracy: fp16 only affects WHICH indices are mined (d2 err ~0.02 vs rival
// gaps ~13); the loss values are recomputed in fp32.

#define NN 4096
#define DD 256
#define MARGIN 0.2f
#define NCHUNK 32            // one 128-col j-tile per chunk
#define BK 64                // K-chunk in halves (2 MFMA substeps)

typedef _Float16 f16;
typedef __attribute__((ext_vector_type(8))) _Float16 f16x8;
typedef __attribute__((ext_vector_type(4))) _Float16 f16x4;
typedef __attribute__((ext_vector_type(4))) float f32x4;
typedef unsigned long long u64;

// ws byte offsets
#define OFF_SQ     64                                    // 16 KB
#define OFF_EH     (OFF_SQ + NN * 4)                     // 2 MB fp16 embeddings
#define OFF_POSB   (OFF_EH + NN * DD * 2)                // 2 MB packed positives
#define OFF_PPV    (OFF_POSB + (NN * (long)NN / 8))      // 512 KB each partial
#define OFF_PPI    (OFF_PPV + NN * NCHUNK * 4)
#define OFF_PNV    (OFF_PPI + NN * NCHUNK * 4)
#define OFF_PNI    (OFF_PNV + NN * NCHUNK * 4)
#define OFF_LOSS   (OFF_PNI + NN * NCHUNK * 4)           // 16 KB per-anchor losses

#define CONV_BLOCKS   (NN / 4)                           // 1024
#define REPACK_BLOCKS 4096                               // 16 elements/thread
#define PREP_BLOCKS   (CONV_BLOCKS + REPACK_BLOCKS)

// ---------------------------------------------------------------------------
// XOR swizzle: row stride 64 halves (128 B = all 32 banks); 16-B granule g of
// row r stored at slot g ^ swz(r). Involution: slot s holds granule s^swz(r).
__device__ __forceinline__ int swz(int r) { return (r ^ (r >> 3)) & 7; }

// 16-B global->LDS DMA (lane dest = lds base + lane*16, wave-uniform base).
__device__ __forceinline__ void dma16(const void* g, void* l) {
  __builtin_amdgcn_global_load_lds(
      (const __attribute__((address_space(1))) void*)g,
      (__attribute__((address_space(3))) void*)l, 16, 0, 0);
}

// ---------------------------------------------------------------------------
// prep: convert (blocks 0..CONV_BLOCKS-1) | repack+sniff (the rest).
// Sniff window: first 16 KB of positives_mask — dense enough in every
// candidate encoding (int32 ~64 ones, u8 ~256, f32 ~64, i64/f64 ~32).
__global__ __launch_bounds__(256)
void prep_kernel(const float* __restrict__ E, const void* __restrict__ pos_raw,
                 f16* __restrict__ Eh, float* __restrict__ sq,
                 u64* __restrict__ posb) {
  const int bid = blockIdx.x;
  const int tid = threadIdx.x;
  if (bid < CONV_BLOCKS) {
    const int row = bid * 4 + (tid >> 6);
    const int lane = tid & 63;
    const float4 v = *(const float4*)&E[(size_t)row * DD + lane * 4];
    f16x4 h;
    h[0] = (f16)v.x; h[1] = (f16)v.y; h[2] = (f16)v.z; h[3] = (f16)v.w;
    *(f16x4*)&Eh[(size_t)row * DD + lane * 4] = h;
    float s = v.x * v.x + v.y * v.y + v.z * v.z + v.w * v.w;
#pragma unroll
    for (int off = 32; off > 0; off >>= 1) s += __shfl_down(s, off);
    if (lane == 0) sq[row] = s;
    return;
  }

  // ---- repack branch ----
  __shared__ int s_ev[4];
  // format sniff: evidence bits 1=u8, 2=f32, 4=f64(odd 1.0-hi), 8=odd-dword
  int ev = 0;
#pragma unroll
  for (int k = 0; k < 16; ++k) {
    const int di = tid + (k << 8);                       // 4096 dwords = 16 KB
    const unsigned int v = ((const unsigned int*)pos_raw)[di];
    if (v & 0xffffff00u) ev |= 1;
    if (v == 0x3f800000u) ev |= 2;
    if (di & 1) {
      if (v == 0x3ff00000u) ev |= 4;
      if (v) ev |= 8;
    }
  }
#pragma unroll
  for (int off = 32; off > 0; off >>= 1) ev |= __shfl_xor(ev, off);
  if ((tid & 63) == 0) s_ev[tid >> 6] = ev;
  __syncthreads();
  ev = s_ev[0] | s_ev[1] | s_ev[2] | s_ev[3];
  int f;                                                  // 0=i32 1=u8 2=f32 3=i64 4=f64
  if (ev & 2) f = 2;
  else if (ev & 4) f = 4;
  else if (ev & 1) f = 1;
  else if (ev & 8) f = 0;
  else f = 3;

  const long long stride = (long long)REPACK_BLOCKS * 256;  // 1,048,576
  const long long base = (long long)(bid - CONV_BLOCKS) * 256 + tid;
#pragma unroll
  for (int it = 0; it < 16; ++it) {
    const long long idx = base + it * stride;
    bool p;
    if (f == 0)      p = ((const unsigned int*)pos_raw)[idx] != 0u;
    else if (f == 1) p = ((const unsigned char*)pos_raw)[idx] != 0;
    else if (f == 2) p = ((const float*)pos_raw)[idx] != 0.f;
    else if (f == 3) p = ((const u64*)pos_raw)[idx] != 0ull;
    else             p = ((const double*)pos_raw)[idx] != 0.0;
    const u64 w = __ballot(p);
    if ((tid & 63) == 0) posb[idx >> 6] = w;
  }
}

// ---------------------------------------------------------------------------
// MFMA Gram + batch-hard mining. 128x128 tile/block; 4 waves in a 2x2 grid,
// each wave a 4x4 grid of 16x16x32_f16 MFMAs. Staging: global_load_lds DMA,
// 8 issues/wave/chunk (A:4, B:4), each issue = 8 rows x 128 B. No staging
// VGPRs -> no spill (round-5 lesson). Epilogue: per-row masked max/min with
// index, quad-butterfly + LDS cross-wave reduce -> per-chunk partials.
__global__ __launch_bounds__(256)
void mine_kernel(const f16* __restrict__ Eh, const float* __restrict__ sq,
                 const u64* __restrict__ posb,
                 float* __restrict__ part_pv, int* __restrict__ part_pi,
                 float* __restrict__ part_nv, int* __restrict__ part_ni) {
  __shared__ union {
    struct { f16 A[128 * BK]; f16 B[128 * BK]; } t;                   // 32 KB
    struct { float pv[2][128]; int pi[2][128];
             float nv[2][128]; int ni[2][128]; } r;                   // 4 KB
  } sm;

  const int tid = threadIdx.x;
  const int lane = tid & 63, wave = tid >> 6;
  const int lx = lane & 15, q = lane >> 4;
  const int wr = wave >> 1, wc = wave & 1;
  const int ib = blockIdx.x & 31, jb = blockIdx.x >> 5;
  const int i0 = ib * 128, j0 = jb * 128;

  f32x4 acc[4][4];
#pragma unroll
  for (int mt = 0; mt < 4; ++mt)
#pragma unroll
    for (int nt = 0; nt < 4; ++nt) acc[mt][nt] = (f32x4)0.f;

  // DMA source pattern: issue i covers rows 8i..8i+7; lane ld = row 8i+(ld>>3),
  // slot ld&7, fetches granule (ld&7)^swz(row) -> swizzled layout lands right.
  const int drow = lane >> 3;            // 0..7 within issue
  const int dslot = lane & 7;

  for (int kk = 0; kk < DD; kk += BK) {
    __syncthreads();                      // prev chunk's frag reads done
#pragma unroll
    for (int t = 0; t < 4; ++t) {
      const int i = wave * 4 + t;         // issue 0..15
      const int r = i * 8 + drow;         // tile row 0..127
      const int g = dslot ^ swz(r);
      dma16(Eh + (size_t)(i0 + r) * DD + kk + g * 8, &sm.t.A[i * 512]);
      dma16(Eh + (size_t)(j0 + r) * DD + kk + g * 8, &sm.t.B[i * 512]);
    }
    __syncthreads();                      // compiler drains vmcnt before barrier
#pragma unroll
    for (int ss = 0; ss < 2; ++ss) {
      f16x8 af[4], bf[4];
#pragma unroll
      for (int mt = 0; mt < 4; ++mt) {
        const int r = wr * 64 + mt * 16 + lx;
        af[mt] = *(const f16x8*)&sm.t.A[r * BK + (((ss * 4 + q) ^ swz(r)) << 3)];
      }
#pragma unroll
      for (int nt = 0; nt < 4; ++nt) {
        const int r = wc * 64 + nt * 16 + lx;
        bf[nt] = *(const f16x8*)&sm.t.B[r * BK + (((ss * 4 + q) ^ swz(r)) << 3)];
      }
#pragma unroll
      for (int mt = 0; mt < 4; ++mt)
#pragma unroll
        for (int nt = 0; nt < 4; ++nt)
          acc[mt][nt] = __builtin_amdgcn_mfma_f32_16x16x32_f16(af[mt], bf[nt], acc[mt][nt], 0, 0, 0);
    }
  }

  // ------- epilogue: d2 + masked mining -------
  float sqj[4];
#pragma unroll
  for (int nt = 0; nt < 4; ++nt) sqj[nt] = sq[j0 + wc * 64 + nt * 16 + lx];
  const int jw = (j0 + wc * 64) >> 6;  // mask word index for this wave's 64 cols

  __syncthreads();  // all frag reads done; LDS becomes the mining buffer

#pragma unroll
  for (int mt = 0; mt < 4; ++mt) {
#pragma unroll
    for (int r = 0; r < 4; ++r) {
      const int lr = wr * 64 + mt * 16 + q * 4 + r;   // local row 0..127
      const int gi = i0 + lr;
      const float sqi = sq[gi];
      const u64 pw = posb[(size_t)gi * (NN / 64) + jw];
      const u64 nw = ~(pw | (((gi >> 6) == jw) ? (1ull << (gi & 63)) : 0ull));
      float pb = -1e30f, nb = 1e30f;
      int pi_ = 1 << 30, ni_ = 1 << 30;
#pragma unroll
      for (int nt = 0; nt < 4; ++nt) {
        const int c = nt * 16 + lx;                    // col within the 64-word
        const int gj = j0 + wc * 64 + c;
        const float d2 = fmaxf(fmaf(-2.f, acc[mt][nt][r], sqi + sqj[nt]), 0.f);
        if ((pw >> c) & 1ull) { if (d2 > pb) { pb = d2; pi_ = gj; } }
        if ((nw >> c) & 1ull) { if (d2 < nb) { nb = d2; ni_ = gj; } }
      }
      // butterfly across the 16 lanes of this quad (offsets < 16 stay in-quad)
#pragma unroll
      for (int off = 1; off < 16; off <<= 1) {
        float ov = __shfl_xor(pb, off); int oi = __shfl_xor(pi_, off);
        if (ov > pb || (ov == pb && oi < pi_)) { pb = ov; pi_ = oi; }
        ov = __shfl_xor(nb, off); oi = __shfl_xor(ni_, off);
        if (ov < nb || (ov == nb && oi < ni_)) { nb = ov; ni_ = oi; }
      }
      if (lx == 0) {
        sm.r.pv[wc][lr] = pb; sm.r.pi[wc][lr] = pi_;
        sm.r.nv[wc][lr] = nb; sm.r.ni[wc][lr] = ni_;
      }
    }
  }

  __syncthreads();
  if (tid < 128) {
    float pv = sm.r.pv[0][tid]; int pi_ = sm.r.pi[0][tid];
    float nv = sm.r.nv[0][tid]; int ni_ = sm.r.ni[0][tid];
    const float pv1 = sm.r.pv[1][tid]; const int pi1 = sm.r.pi[1][tid];
    const float nv1 = sm.r.nv[1][tid]; const int ni1 = sm.r.ni[1][tid];
    if (pv1 > pv) { pv = pv1; pi_ = pi1; }   // wc=0 has lower cols: ties keep wc0
    if (nv1 < nv) { nv = nv1; ni_ = ni1; }
    const size_t o = (size_t)(i0 + tid) * NCHUNK + jb;
    part_pv[o] = pv; part_pi[o] = pi_;
    part_nv[o] = nv; part_ni[o] = ni_;
  }
}

// ---------------------------------------------------------------------------
// Fused combine + finalize: one wave per anchor. Lanes 0..31 reduce the 32
// positive-chunk partials (argmax), lanes 32..63 the negative ones (argmin
// via negated key); ties keep the smallest index (reference first-index
// semantics; chunk order == index order). Then fp32 recompute of the three
// distances -> loss[a]. No atomics, no fences.
__global__ __launch_bounds__(256)
void finalize_kernel(const float* __restrict__ E, const float* __restrict__ sq,
                     const float* __restrict__ ppv, const int* __restrict__ ppi,
                     const float* __restrict__ pnv, const int* __restrict__ pni,
                     float* __restrict__ loss) {
  const int tid = threadIdx.x;
  const int a = blockIdx.x * 4 + (tid >> 6);
  const int lane = tid & 63;
  const int ch = lane & 31;
  float key; int idx;
  if (lane < 32) { key = ppv[(size_t)a * NCHUNK + ch]; idx = ppi[(size_t)a * NCHUNK + ch]; }
  else           { key = -pnv[(size_t)a * NCHUNK + ch]; idx = pni[(size_t)a * NCHUNK + ch]; }
#pragma unroll
  for (int off = 1; off < 32; off <<= 1) {   // stays within each 32-lane half
    const float ok = __shfl_xor(key, off); const int oi = __shfl_xor(idx, off);
    if (ok > key || (ok == key && oi < idx)) { key = ok; idx = oi; }
  }
  const int p = __shfl(idx, 0);
  const int n = __shfl(idx, 32);
  const bool valid = (p < NN) && (n < NN);
  const int pp = valid ? p : 0, nn = valid ? n : 0;

  const float4 xa = *(const float4*)&E[(size_t)a * DD + lane * 4];
  const float4 xp = *(const float4*)&E[(size_t)pp * DD + lane * 4];
  const float4 xn = *(const float4*)&E[(size_t)nn * DD + lane * 4];
  float dap = xa.x * xp.x + xa.y * xp.y + xa.z * xp.z + xa.w * xp.w;
  float dan = xa.x * xn.x + xa.y * xn.y + xa.z * xn.z + xa.w * xn.w;
  float dpn = xp.x * xn.x + xp.y * xn.y + xp.z * xn.z + xp.w * xn.w;
#pragma unroll
  for (int off = 32; off > 0; off >>= 1) {
    dap += __shfl_down(dap, off);
    dan += __shfl_down(dan, off);
    dpn += __shfl_down(dpn, off);
  }
  if (lane == 0) {
    float l = 0.f;
    if (valid) {
      const float d2ap = fmaxf(sq[a] + sq[pp] - 2.f * dap, 0.f);
      const float d2an = fmaxf(sq[a] + sq[nn] - 2.f * dan, 0.f);
      const float d2pn = fmaxf(sq[pp] + sq[nn] - 2.f * dpn, 0.f);
      l = fmaxf(sqrtf(d2ap) - fminf(sqrtf(d2an), sqrtf(d2pn)) + MARGIN, 0.f);
    }
    loss[a] = l;
  }
}

// ---------------------------------------------------------------------------
// Single block: sum + nonzero-count over loss[NN], write the scalar output.
__global__ __launch_bounds__(1024)
void reduce_kernel(const float* __restrict__ loss, float* __restrict__ out) {
  __shared__ float s_sum[16], s_cnt[16];
  const int tid = threadIdx.x;
  const float4 v = *(const float4*)&loss[tid * 4];
  float s = v.x + v.y + v.z + v.w;
  float c = (v.x > 0.f) + (v.y > 0.f) + (v.z > 0.f) + (v.w > 0.f);
#pragma unroll
  for (int off = 32; off > 0; off >>= 1) {
    s += __shfl_down(s, off);
    c += __shfl_down(c, off);
  }
  if ((tid & 63) == 0) { s_sum[tid >> 6] = s; s_cnt[tid >> 6] = c; }
  __syncthreads();
  if (tid == 0) {
    float ts = 0.f, tc = 0.f;
#pragma unroll
    for (int w = 0; w < 16; ++w) { ts += s_sum[w]; tc += s_cnt[w]; }
    out[0] = (tc > 0.f) ? (ts / fmaxf(tc, 1.f)) : 0.f;
  }
}

// ---------------------------------------------------------------------------
extern "C" void kernel_launch(void* const* d_in, const int* in_sizes, int n_in,
                              void* d_out, int out_size, void* d_ws, size_t ws_size,
                              hipStream_t stream) {
  const float* E = (const float*)d_in[0];
  const void* posm = d_in[1];
  float* out = (float*)d_out;
  char* ws = (char*)d_ws;

  float* sq = (float*)(ws + OFF_SQ);
  f16* Eh = (f16*)(ws + OFF_EH);
  u64* posb = (u64*)(ws + OFF_POSB);
  float* ppv = (float*)(ws + OFF_PPV);
  int* ppi = (int*)(ws + OFF_PPI);
  float* pnv = (float*)(ws + OFF_PNV);
  int* pni = (int*)(ws + OFF_PNI);
  float* loss = (float*)(ws + OFF_LOSS);

  prep_kernel<<<PREP_BLOCKS, 256, 0, stream>>>(E, posm, Eh, sq, posb);
  mine_kernel<<<32 * NCHUNK, 256, 0, stream>>>(Eh, sq, posb, ppv, ppi, pnv, pni);
  finalize_kernel<<<NN / 4, 256, 0, stream>>>(E, sq, ppv, ppi, pnv, pni, loss);
  reduce_kernel<<<1, 1024, 0, stream>>>(loss, out);
}

// Round 8
// 179.207 us; speedup vs baseline: 1.5125x; 1.1761x over previous
//
#include <hip/hip_runtime.h>
#include <math.h>

// BatchHardTripletMarginLoss on MI355X — round 8: transposed mining epilogue.
// Pipeline (all on `stream`, graph-capture safe):
//   prep    : [blocks 0..1023] E fp32->fp16 + sq
//             [blocks 1024..5119] per-block mask-format sniff + positives_mask
//             -> packed bitmask via __ballot (neg = ~(pos|eye), derived)
//   mine    : fp16 MFMA Gram 128x128/block, BK=64, global_load_lds staging,
//             XOR-swizzled LDS. MFMA operands SWAPPED (acc = mfma(bf, af)) so
//             each lane owns an ANCHOR column: mining reduces 16 values
//             in-thread + 2-step butterfly (round-7 epilogue was 256 shuffles
//             per wave = the 30+ us floor). (d2bits,~gj) packed in one u64 key
//             -> value+index+tiebreak in a single max; ties = smallest index
//             globally (reference argmax/argmin semantics).
//   finalize: u64 key max across 32 chunks + fp32 distance recompute -> loss[a]
//   reduce  : single-block tree-reduce of loss[] -> out
// Accuracy: fp16 only affects WHICH indices are mined (d2 err ~0.02 vs rival
// gaps ~13); the loss values are recomputed in fp32.

#define NN 4096
#define DD 256
#define MARGIN 0.2f
#define NCHUNK 32            // one 128-col j-tile per chunk
#define BK 64                // K-chunk in halves (2 MFMA substeps)

typedef _Float16 f16;
typedef __attribute__((ext_vector_type(8))) _Float16 f16x8;
typedef __attribute__((ext_vector_type(4))) _Float16 f16x4;
typedef __attribute__((ext_vector_type(4))) float f32x4;
typedef unsigned long long u64;
typedef unsigned int u32;

// ws byte offsets
#define OFF_SQ     64                                    // 16 KB
#define OFF_EH     (OFF_SQ + NN * 4)                     // 2 MB fp16 embeddings
#define OFF_POSB   (OFF_EH + NN * DD * 2)                // 2 MB packed positives
#define OFF_PPK    (OFF_POSB + (NN * (long)NN / 8))      // 1 MB u64 pos keys [chunk][anchor]
#define OFF_PNK    (OFF_PPK + NN * NCHUNK * 8)           // 1 MB u64 neg keys
#define OFF_LOSS   (OFF_PNK + NN * NCHUNK * 8)           // 16 KB per-anchor losses

#define CONV_BLOCKS   (NN / 4)                           // 1024
#define REPACK_BLOCKS 4096                               // 16 elements/thread
#define PREP_BLOCKS   (CONV_BLOCKS + REPACK_BLOCKS)

// ---------------------------------------------------------------------------
// XOR swizzle: row stride 64 halves (128 B = all 32 banks); 16-B granule g of
// row r stored at slot g ^ swz(r). Involution: slot s holds granule s^swz(r).
__device__ __forceinline__ int swz(int r) { return (r ^ (r >> 3)) & 7; }

// 16-B global->LDS DMA (lane dest = lds base + lane*16, wave-uniform base).
__device__ __forceinline__ void dma16(const void* g, void* l) {
  __builtin_amdgcn_global_load_lds(
      (const __attribute__((address_space(1))) void*)g,
      (__attribute__((address_space(3))) void*)l, 16, 0, 0);
}

// ---------------------------------------------------------------------------
// prep: convert (blocks 0..CONV_BLOCKS-1) | repack+sniff (the rest).
__global__ __launch_bounds__(256)
void prep_kernel(const float* __restrict__ E, const void* __restrict__ pos_raw,
                 f16* __restrict__ Eh, float* __restrict__ sq,
                 u64* __restrict__ posb) {
  const int bid = blockIdx.x;
  const int tid = threadIdx.x;
  if (bid < CONV_BLOCKS) {
    const int row = bid * 4 + (tid >> 6);
    const int lane = tid & 63;
    const float4 v = *(const float4*)&E[(size_t)row * DD + lane * 4];
    f16x4 h;
    h[0] = (f16)v.x; h[1] = (f16)v.y; h[2] = (f16)v.z; h[3] = (f16)v.w;
    *(f16x4*)&Eh[(size_t)row * DD + lane * 4] = h;
    float s = v.x * v.x + v.y * v.y + v.z * v.z + v.w * v.w;
#pragma unroll
    for (int off = 32; off > 0; off >>= 1) s += __shfl_down(s, off);
    if (lane == 0) sq[row] = s;
    return;
  }

  // ---- repack branch ----
  __shared__ int s_ev[4];
  // format sniff: evidence bits 1=u8, 2=f32, 4=f64(odd 1.0-hi), 8=odd-dword
  int ev = 0;
#pragma unroll
  for (int k = 0; k < 16; ++k) {
    const int di = tid + (k << 8);                       // 4096 dwords = 16 KB
    const u32 v = ((const u32*)pos_raw)[di];
    if (v & 0xffffff00u) ev |= 1;
    if (v == 0x3f800000u) ev |= 2;
    if (di & 1) {
      if (v == 0x3ff00000u) ev |= 4;
      if (v) ev |= 8;
    }
  }
#pragma unroll
  for (int off = 32; off > 0; off >>= 1) ev |= __shfl_xor(ev, off);
  if ((tid & 63) == 0) s_ev[tid >> 6] = ev;
  __syncthreads();
  ev = s_ev[0] | s_ev[1] | s_ev[2] | s_ev[3];
  int f;                                                  // 0=i32 1=u8 2=f32 3=i64 4=f64
  if (ev & 2) f = 2;
  else if (ev & 4) f = 4;
  else if (ev & 1) f = 1;
  else if (ev & 8) f = 0;
  else f = 3;

  const long long stride = (long long)REPACK_BLOCKS * 256;  // 1,048,576
  const long long base = (long long)(bid - CONV_BLOCKS) * 256 + tid;
#pragma unroll
  for (int it = 0; it < 16; ++it) {
    const long long idx = base + it * stride;
    bool p;
    if (f == 0)      p = ((const u32*)pos_raw)[idx] != 0u;
    else if (f == 1) p = ((const unsigned char*)pos_raw)[idx] != 0;
    else if (f == 2) p = ((const float*)pos_raw)[idx] != 0.f;
    else if (f == 3) p = ((const u64*)pos_raw)[idx] != 0ull;
    else             p = ((const double*)pos_raw)[idx] != 0.0;
    const u64 w = __ballot(p);
    if ((tid & 63) == 0) posb[idx >> 6] = w;
  }
}

// ---------------------------------------------------------------------------
// MFMA Gram + batch-hard mining. 128x128 tile/block; 4 waves in a 2x2 grid,
// each wave a 4x4 grid of 16x16x32_f16 MFMAs with SWAPPED operands:
//   acc[mt][nt](q,r,lx) = S[j0 + wc*64 + nt*16 + q*4 + r][i0 + wr*64 + mt*16 + lx]
// so lane lx owns anchor column (i), with 16 j-values (nt x r) in-thread and
// 4 q-groups covering 64 j per wave. Epilogue: in-thread u64-key max +
// 2-step q-butterfly + tiny LDS wc-combine -> per-chunk u64 key partials.
__global__ __launch_bounds__(256)
void mine_kernel(const f16* __restrict__ Eh, const float* __restrict__ sq,
                 const u64* __restrict__ posb,
                 u64* __restrict__ part_p, u64* __restrict__ part_n) {
  __shared__ union {
    struct { f16 A[128 * BK]; f16 B[128 * BK]; } t;                   // 32 KB
    struct { u64 pk[2][128]; u64 nk[2][128]; } r;                     // 4 KB
  } sm;

  const int tid = threadIdx.x;
  const int lane = tid & 63, wave = tid >> 6;
  const int lx = lane & 15, q = lane >> 4;
  const int wr = wave >> 1, wc = wave & 1;
  const int ib = blockIdx.x & 31, jb = blockIdx.x >> 5;
  const int i0 = ib * 128, j0 = jb * 128;

  f32x4 acc[4][4];
#pragma unroll
  for (int mt = 0; mt < 4; ++mt)
#pragma unroll
    for (int nt = 0; nt < 4; ++nt) acc[mt][nt] = (f32x4)0.f;

  // DMA source pattern: issue i covers rows 8i..8i+7; lane ld = row 8i+(ld>>3),
  // slot ld&7, fetches granule (ld&7)^swz(row) -> swizzled layout lands right.
  const int drow = lane >> 3;            // 0..7 within issue
  const int dslot = lane & 7;

  for (int kk = 0; kk < DD; kk += BK) {
    __syncthreads();                      // prev chunk's frag reads done
#pragma unroll
    for (int t = 0; t < 4; ++t) {
      const int i = wave * 4 + t;         // issue 0..15
      const int r = i * 8 + drow;         // tile row 0..127
      const int g = dslot ^ swz(r);
      dma16(Eh + (size_t)(i0 + r) * DD + kk + g * 8, &sm.t.A[i * 512]);
      dma16(Eh + (size_t)(j0 + r) * DD + kk + g * 8, &sm.t.B[i * 512]);
    }
    __syncthreads();                      // compiler drains vmcnt before barrier
#pragma unroll
    for (int ss = 0; ss < 2; ++ss) {
      f16x8 af[4], bf[4];
#pragma unroll
      for (int mt = 0; mt < 4; ++mt) {
        const int r = wr * 64 + mt * 16 + lx;
        af[mt] = *(const f16x8*)&sm.t.A[r * BK + (((ss * 4 + q) ^ swz(r)) << 3)];
      }
#pragma unroll
      for (int nt = 0; nt < 4; ++nt) {
        const int r = wc * 64 + nt * 16 + lx;
        bf[nt] = *(const f16x8*)&sm.t.B[r * BK + (((ss * 4 + q) ^ swz(r)) << 3)];
      }
      // SWAPPED: bf first -> D rows = j, D cols = i (anchor per lane)
#pragma unroll
      for (int mt = 0; mt < 4; ++mt)
#pragma unroll
        for (int nt = 0; nt < 4; ++nt)
          acc[mt][nt] = __builtin_amdgcn_mfma_f32_16x16x32_f16(bf[nt], af[mt], acc[mt][nt], 0, 0, 0);
    }
  }

  // ------- epilogue: per-anchor u64-key mining -------
  // anchor (per lane, per mt): gi = i0 + wr*64 + mt*16 + lx
  // j (per value):             gj = j0 + wc*64 + nt*16 + q*4 + r
  float sqi_[4];
  u64 pw_[4], nw_[4];
  const int jw = (j0 + wc * 64) >> 6;    // mask word for this wave's 64 cols
#pragma unroll
  for (int mt = 0; mt < 4; ++mt) {
    const int gi = i0 + wr * 64 + mt * 16 + lx;
    sqi_[mt] = sq[gi];
    const u64 pw = posb[(size_t)gi * (NN / 64) + jw];
    const u64 eye = ((gi >> 6) == jw) ? (1ull << (gi & 63)) : 0ull;
    pw_[mt] = pw;
    nw_[mt] = ~(pw | eye);
  }
  f32x4 sqjv[4];
#pragma unroll
  for (int nt = 0; nt < 4; ++nt)
    sqjv[nt] = *(const f32x4*)&sq[j0 + wc * 64 + nt * 16 + q * 4];
  const u32 jlo_base = ~(u32)(j0 + wc * 64 + q * 4);   // lo = jlo_base - (nt*16+r) = ~gj

  u64 pk[4] = {0ull, 0ull, 0ull, 0ull};   // key 0 = no candidate
  u64 nk[4] = {0ull, 0ull, 0ull, 0ull};
#pragma unroll
  for (int mt = 0; mt < 4; ++mt) {
#pragma unroll
    for (int nt = 0; nt < 4; ++nt) {
#pragma unroll
      for (int r = 0; r < 4; ++r) {
        const int c = nt * 16 + q * 4 + r;             // bit within the 64-col window
        const float d2 = fmaxf(fmaf(-2.f, acc[mt][nt][r], sqi_[mt] + sqjv[nt][r]), 0.f);
        const u32 hi = __float_as_uint(d2);            // d2>=0: bits monotone
        const u32 lo = jlo_base - (u32)(nt * 16 + r);  // ~gj: ties -> smaller index
        const u64 key = ((u64)hi << 32) | lo;
        const u64 nkey = ((u64)(~hi) << 32) | lo;
        if ((pw_[mt] >> c) & 1ull) pk[mt] = key > pk[mt] ? key : pk[mt];
        if ((nw_[mt] >> c) & 1ull) nk[mt] = nkey > nk[mt] ? nkey : nk[mt];
      }
    }
  }
  // butterfly across the 4 q-groups (lanes lx, lx+16, lx+32, lx+48)
#pragma unroll
  for (int mt = 0; mt < 4; ++mt) {
#pragma unroll
    for (int off = 16; off < 64; off <<= 1) {
      u64 o = __shfl_xor(pk[mt], off);
      if (o > pk[mt]) pk[mt] = o;
      o = __shfl_xor(nk[mt], off);
      if (o > nk[mt]) nk[mt] = o;
    }
  }

  __syncthreads();  // all frag reads done; LDS becomes the reduce buffer
  if (q == 0) {
#pragma unroll
    for (int mt = 0; mt < 4; ++mt) {
      const int lr = wr * 64 + mt * 16 + lx;           // local anchor 0..127
      sm.r.pk[wc][lr] = pk[mt];
      sm.r.nk[wc][lr] = nk[mt];
    }
  }
  __syncthreads();
  if (tid < 128) {
    const u64 p0 = sm.r.pk[0][tid], p1 = sm.r.pk[1][tid];
    const u64 n0 = sm.r.nk[0][tid], n1 = sm.r.nk[1][tid];
    part_p[(size_t)jb * NN + i0 + tid] = p0 > p1 ? p0 : p1;
    part_n[(size_t)jb * NN + i0 + tid] = n0 > n1 ? n0 : n1;
  }
}

// ---------------------------------------------------------------------------
// finalize: one wave per anchor. Lanes 0..31 max-reduce the 32 positive-chunk
// u64 keys, lanes 32..63 the negative ones (keys already encode value+index+
// tiebreak; chunk order needs no special handling). Unpack indices, fp32
// recompute of the three distances -> loss[a]. No atomics, no fences.
__global__ __launch_bounds__(256)
void finalize_kernel(const float* __restrict__ E, const float* __restrict__ sq,
                     const u64* __restrict__ part_p, const u64* __restrict__ part_n,
                     float* __restrict__ loss) {
  const int tid = threadIdx.x;
  const int a = blockIdx.x * 4 + (tid >> 6);
  const int lane = tid & 63;
  const int ch = lane & 31;
  u64 key = (lane < 32) ? part_p[(size_t)ch * NN + a] : part_n[(size_t)ch * NN + a];
#pragma unroll
  for (int off = 1; off < 32; off <<= 1) {   // stays within each 32-lane half
    const u64 o = __shfl_xor(key, off);
    if (o > key) key = o;
  }
  const u64 pkey = __shfl(key, 0);
  const u64 nkey = __shfl(key, 32);
  const bool valid = (pkey != 0ull) && (nkey != 0ull);
  const int p = (int)(~(u32)pkey);           // lo = ~gj
  const int n = (int)(~(u32)nkey);
  const int pp = valid ? p : 0, nn = valid ? n : 0;

  const float4 xa = *(const float4*)&E[(size_t)a * DD + lane * 4];
  const float4 xp = *(const float4*)&E[(size_t)pp * DD + lane * 4];
  const float4 xn = *(const float4*)&E[(size_t)nn * DD + lane * 4];
  float dap = xa.x * xp.x + xa.y * xp.y + xa.z * xp.z + xa.w * xp.w;
  float dan = xa.x * xn.x + xa.y * xn.y + xa.z * xn.z + xa.w * xn.w;
  float dpn = xp.x * xn.x + xp.y * xn.y + xp.z * xn.z + xp.w * xn.w;
#pragma unroll
  for (int off = 32; off > 0; off >>= 1) {
    dap += __shfl_down(dap, off);
    dan += __shfl_down(dan, off);
    dpn += __shfl_down(dpn, off);
  }
  if (lane == 0) {
    float l = 0.f;
    if (valid) {
      const float d2ap = fmaxf(sq[a] + sq[pp] - 2.f * dap, 0.f);
      const float d2an = fmaxf(sq[a] + sq[nn] - 2.f * dan, 0.f);
      const float d2pn = fmaxf(sq[pp] + sq[nn] - 2.f * dpn, 0.f);
      l = fmaxf(sqrtf(d2ap) - fminf(sqrtf(d2an), sqrtf(d2pn)) + MARGIN, 0.f);
    }
    loss[a] = l;
  }
}

// ---------------------------------------------------------------------------
// Single block: sum + nonzero-count over loss[NN], write the scalar output.
__global__ __launch_bounds__(1024)
void reduce_kernel(const float* __restrict__ loss, float* __restrict__ out) {
  __shared__ float s_sum[16], s_cnt[16];
  const int tid = threadIdx.x;
  const float4 v = *(const float4*)&loss[tid * 4];
  float s = v.x + v.y + v.z + v.w;
  float c = (v.x > 0.f) + (v.y > 0.f) + (v.z > 0.f) + (v.w > 0.f);
#pragma unroll
  for (int off = 32; off > 0; off >>= 1) {
    s += __shfl_down(s, off);
    c += __shfl_down(c, off);
  }
  if ((tid & 63) == 0) { s_sum[tid >> 6] = s; s_cnt[tid >> 6] = c; }
  __syncthreads();
  if (tid == 0) {
    float ts = 0.f, tc = 0.f;
#pragma unroll
    for (int w = 0; w < 16; ++w) { ts += s_sum[w]; tc += s_cnt[w]; }
    out[0] = (tc > 0.f) ? (ts / fmaxf(tc, 1.f)) : 0.f;
  }
}

// ---------------------------------------------------------------------------
extern "C" void kernel_launch(void* const* d_in, const int* in_sizes, int n_in,
                              void* d_out, int out_size, void* d_ws, size_t ws_size,
                              hipStream_t stream) {
  const float* E = (const float*)d_in[0];
  const void* posm = d_in[1];
  float* out = (float*)d_out;
  char* ws = (char*)d_ws;

  float* sq = (float*)(ws + OFF_SQ);
  f16* Eh = (f16*)(ws + OFF_EH);
  u64* posb = (u64*)(ws + OFF_POSB);
  u64* ppk = (u64*)(ws + OFF_PPK);
  u64* pnk = (u64*)(ws + OFF_PNK);
  float* loss = (float*)(ws + OFF_LOSS);

  prep_kernel<<<PREP_BLOCKS, 256, 0, stream>>>(E, posm, Eh, sq, posb);
  mine_kernel<<<32 * NCHUNK, 256, 0, stream>>>(Eh, sq, posb, ppk, pnk);
  finalize_kernel<<<NN / 4, 256, 0, stream>>>(E, sq, ppk, pnk, loss);
  reduce_kernel<<<1, 1024, 0, stream>>>(loss, out);
}